// Round 5
// baseline (335.923 us; speedup 1.0000x reference)
//
#include <hip/hip_runtime.h>
#include <hip/hip_fp16.h>
#include <math.h>

#define N_NODES 50000
#define N_EDGES 800000
#define NB 782            // ceil(50000/64) buckets of 64 dst nodes
#define CH 4096           // edges per k_bucket block
#define CAP 2048          // arena slots per bucket (Poisson(1024) -> 2x slack)
#define BUCKET_BLOCKS 196 // ceil(800000/4096)
#define CAST_BLOCKS 6250  // N_NODES*128/4/256
#define PREPW_BLOCKS 192  // 3 * 16384/256
#define FILL_GRID (NB + CAST_BLOCKS + PREPW_BLOCKS)
#define FB 3125           // 50000/16 fused-layer blocks (16 nodes each, exact)

typedef _Float16 half8 __attribute__((ext_vector_type(8)));
typedef float floatx4 __attribute__((ext_vector_type(4)));
typedef unsigned uintx4 __attribute__((ext_vector_type(4)));

// ---- pass 1: LDS-staged bucket scatter into padded arena ------------------
__global__ __launch_bounds__(256) void k_bucket(const int* __restrict__ src,
                                                const int* __restrict__ dst,
                                                int* __restrict__ gcur,
                                                unsigned* __restrict__ arena) {
    __shared__ int cntA[NB];
    __shared__ int lofs[NB];
    __shared__ int gbase[NB];
    __shared__ int part[256];
    __shared__ unsigned buf[CH];
    const int t = threadIdx.x;
    const int ebase = blockIdx.x * CH;
    const int chunkN = min(CH, N_EDGES - ebase);

    for (int i = t; i < NB; i += 256) cntA[i] = 0;
    __syncthreads();
    for (int i = t; i < chunkN; i += 256)
        atomicAdd(&cntA[dst[ebase + i] >> 6], 1);
    __syncthreads();
    int c[4];
    int s = 0;
#pragma unroll
    for (int q = 0; q < 4; ++q) {
        int idx = t * 4 + q;
        c[q] = (idx < NB) ? cntA[idx] : 0;
        s += c[q];
    }
    part[t] = s;
    __syncthreads();
    for (int d = 1; d < 256; d <<= 1) {
        int u = (t >= d) ? part[t - d] : 0;
        __syncthreads();
        part[t] += u;
        __syncthreads();
    }
    int run = (t > 0) ? part[t - 1] : 0;
#pragma unroll
    for (int q = 0; q < 4; ++q) {
        int idx = t * 4 + q;
        if (idx < NB) {
            lofs[idx] = run;
            run += c[q];
            gbase[idx] = (c[q] > 0) ? atomicAdd(&gcur[idx], c[q]) : 0;
            cntA[idx] = 0;  // reuse as placement cursor
        }
    }
    __syncthreads();
    for (int i = t; i < chunkN; i += 256) {
        int d = dst[ebase + i];
        int sv = src[ebase + i];
        int b = d >> 6;
        int pos = atomicAdd(&cntA[b], 1);
        buf[lofs[b] + pos] = ((unsigned)d << 16) | (unsigned)sv;
    }
    __syncthreads();
    for (int i = t; i < chunkN; i += 256) {
        unsigned v = buf[i];
        int b = (int)(v >> 16) >> 6;
        int q = i - lofs[b];
        int p = gbase[b] + q;
        if (p < CAP) arena[((size_t)b << 11) + p] = v;
    }
}

// ---- pass 2 (fused): bucket finalize | x->fp16 cast | W->fp16 W^T ---------
__global__ __launch_bounds__(256) void k_fill3prep(
    const unsigned* __restrict__ arena, const int* __restrict__ gcur,
    unsigned* __restrict__ packed, float* __restrict__ dinv,
    unsigned short* __restrict__ eidx, const float* __restrict__ x,
    __half* __restrict__ xh, const float* __restrict__ W0,
    const float* __restrict__ W1, const float* __restrict__ W2,
    __half* __restrict__ WT) {
    const int t = threadIdx.x;
    if (blockIdx.x < NB) {
        const int b = blockIdx.x;
        __shared__ int cnt64[64];
        __shared__ int cur64[64];
        if (t < 64) cnt64[t] = 0;
        __syncthreads();
        const int seglen = min(gcur[b], CAP);
        const unsigned* seg = arena + ((size_t)b << 11);
        for (int i = t; i < seglen; i += 256)
            atomicAdd(&cnt64[(seg[i] >> 16) & 63], 1);
        __syncthreads();
        if (t < 64) {  // one wave: prefix scan of 64 counts
            int v = cnt64[t];
            int p = v;
#pragma unroll
            for (int d = 1; d < 64; d <<= 1) {
                int u = __shfl_up(p, d, 64);
                if (t >= d) p += u;
            }
            int excl = p - v;
            int node = b * 64 + t;
            if (node < N_NODES) {
                packed[node] =
                    ((unsigned)((b << 11) + excl) << 11) | (unsigned)v;
                dinv[node] = rsqrtf((float)v + 2.0f);  // improved: +2
            }
            cur64[t] = excl;
        }
        __syncthreads();
        const int base = b << 11;
        for (int i = t; i < seglen; i += 256) {
            unsigned v = seg[i];
            int d = (int)(v >> 16) & 63;
            int pos = atomicAdd(&cur64[d], 1);
            eidx[base + pos] = (unsigned short)(v & 0xFFFFu);
        }
    } else if (blockIdx.x < NB + CAST_BLOCKS) {
        int i = (blockIdx.x - NB) * 256 + t;  // float4-granular, exact
        float4 v = *(const float4*)&x[(size_t)i * 4];
        union { ushort4 u; __half h[4]; } p;
        p.h[0] = __float2half(v.x); p.h[1] = __float2half(v.y);
        p.h[2] = __float2half(v.z); p.h[3] = __float2half(v.w);
        *(ushort4*)&xh[(size_t)i * 4] = p.u;
    } else {
        int idx = blockIdx.x - NB - CAST_BLOCKS;  // 0..191
        int which = idx >> 6;
        const float* W = (which == 0) ? W0 : (which == 1) ? W1 : W2;
        int i = (idx & 63) * 256 + t;  // 16384 per matrix: i = k*128 + n
        int k = i >> 7, n = i & 127;
        int np = ((n & 7) << 4) + (n >> 3);  // inverse of perm(n')=(n'&15)*8+(n'>>4)
        WT[which * 128 * 128 + np * 128 + k] = __float2half(W[i]);
    }
}

// ====== fused layer: t = 2*p_r + sum p_src  ->  p_next = relu(dv*(dv*tW+b))
// 16 lanes/node (each lane owns 8 features = 1 uint4/row), 16 nodes/block.
// 50000 = 3125*16 exactly -> no bounds checks. Register budget engineered
// under the 64-VGPR occupancy cliff (acc 8 + staging 8x uint4 = 32 + misc):
// __launch_bounds__(256,8) -> 32 waves/CU (4x the previous 76-VGPR config).
template <bool SC>
__global__ __launch_bounds__(256, 8) void k_fused(
    const __half* __restrict__ pin, const __half* __restrict__ WTl,
    const float* __restrict__ dinv, const unsigned* __restrict__ packed,
    const unsigned short* __restrict__ eidx, const float* __restrict__ bias,
    __half* __restrict__ pout) {
    __shared__ __half tl[16 * 136];  // +8 pad: conflict-free b128 r/w
    const int t = threadIdx.x;
    const int g = t >> 4;   // node-in-block 0..15
    const int l = t & 15;   // lane-in-group; owns features l*8..l*8+7
    const int r = blockIdx.x * 16 + g;
    const int e8 = l & 7;

    float acc[8];
    {
        uint4 sv = *(const uint4*)&pin[(size_t)r * 128 + l * 8];
        float s2 = SC ? 2.f * dinv[r] : 2.f;
        union { uint4 u; __half2 h2[4]; } v;
        v.u = sv;
#pragma unroll
        for (int q = 0; q < 4; ++q) {
            float2 w = __half22float2(v.h2[q]);
            acc[2 * q] = s2 * w.x;
            acc[2 * q + 1] = s2 * w.y;
        }
    }
    unsigned pk = packed[r];
    int i = (int)(pk >> 11);
    int end = i + (int)(pk & 2047u);
    // 8-edge batches: 8 outstanding uint4 per lane
    for (; i + 8 <= end; i += 8) {
        int my = (int)__builtin_nontemporal_load(&eidx[i + e8]);
        uint4 va[8];
        float ds8[8];
#pragma unroll
        for (int j = 0; j < 8; ++j) {
            int s0 = __shfl(my, j, 16);
            va[j] = *(const uint4*)&pin[(size_t)s0 * 128 + l * 8];
            if (SC) ds8[j] = dinv[s0];
        }
#pragma unroll
        for (int j = 0; j < 8; ++j) {
            union { uint4 u; __half2 h2[4]; } v;
            v.u = va[j];
            float s = SC ? ds8[j] : 1.f;
#pragma unroll
            for (int q = 0; q < 4; ++q) {
                float2 w = __half22float2(v.h2[q]);
                acc[2 * q] += s * w.x;
                acc[2 * q + 1] += s * w.y;
            }
        }
    }
    if (i < end) {
        int n = end - i;
        int my = (e8 < n) ? (int)eidx[i + e8] : 0;
        for (int j = 0; j < n; ++j) {
            int s0 = __shfl(my, j, 16);
            uint4 u = *(const uint4*)&pin[(size_t)s0 * 128 + l * 8];
            float s = SC ? dinv[s0] : 1.f;
            union { uint4 uu; __half2 h2[4]; } v;
            v.uu = u;
#pragma unroll
            for (int q = 0; q < 4; ++q) {
                float2 w = __half22float2(v.h2[q]);
                acc[2 * q] += s * w.x;
                acc[2 * q + 1] += s * w.y;
            }
        }
    }
    // t -> LDS (fp16): one 16B write per lane
    {
        union { uintx4 u; __half h[8]; } p;
#pragma unroll
        for (int j = 0; j < 8; ++j) p.h[j] = __float2half(acc[j]);
        *(uintx4*)&tl[g * 136 + l * 8] = p.u;
    }
    __syncthreads();

    // MFMA: M=16, N=128, K=128; 4 waves, wave w covers features nt={2w,2w+1}
    const int wave = t >> 6;
    const int lane = t & 63;
    const int m = lane & 15;
    const int quad = lane >> 4;
    floatx4 a4[2] = {};
#pragma unroll
    for (int kb = 0; kb < 4; ++kb) {
        half8 af = *(const half8*)&tl[m * 136 + quad * 8 + kb * 32];
#pragma unroll
        for (int j = 0; j < 2; ++j) {
            half8 bf = *(const half8*)&WTl[(size_t)((2 * wave + j) * 16 + m) * 128 +
                                           kb * 32 + quad * 8];
            a4[j] = __builtin_amdgcn_mfma_f32_16x16x32_f16(af, bf, a4[j], 0, 0, 0);
        }
    }
    // feature f = 8m + 2*wave + j ; node = block*16 + quad*4 + rr
    const int f0 = 8 * m + 2 * wave;
    const float2 bi = *(const float2*)&bias[f0];
    const int nb0 = blockIdx.x * 16 + quad * 4;
#pragma unroll
    for (int rr = 0; rr < 4; ++rr) {
        int node = nb0 + rr;
        float dv = dinv[node];
        union { unsigned u; __half h[2]; } o;
        o.h[0] = __float2half(fmaxf(dv * (dv * a4[0][rr] + bi.x), 0.f));
        o.h[1] = __float2half(fmaxf(dv * (dv * a4[1][rr] + bi.y), 0.f));
        *(unsigned*)&pout[(size_t)node * 128 + f0] = o.u;
    }
}

// ---- dense transform, F_out = 16 (last layer): p3 fp16 in, fp32 out -------
// input is pre-scaled p3 = dinv (.) h3, so (p3 W3) == dinv (.) (h3 W3): no
// dinv multiply here; gather4 consumes it unchanged.
__global__ __launch_bounds__(256) void k_gemm16(const __half* __restrict__ in,
                                                const float* __restrict__ W,
                                                float* __restrict__ hs) {
    __shared__ float Wt[16 * 132];
    const int tid = threadIdx.x;
    for (int i = tid; i < 128 * 16; i += 256) {
        int k = i >> 4, c = i & 15;
        Wt[c * 132 + k] = W[i];
    }
    __syncthreads();
    int gid = blockIdx.x * 256 + tid;  // grid exactly 50000*16
    int r = gid >> 4, c = gid & 15;
    const __half* arow = &in[(size_t)r * 128];
    const float* wrow = &Wt[c * 132];
    float acc = 0.f;
#pragma unroll
    for (int k0 = 0; k0 < 128; k0 += 8) {
        union { uint4 u; __half2 h2[4]; } p;
        p.u = *(const uint4*)&arow[k0];
#pragma unroll
        for (int q = 0; q < 4; ++q) {
            float2 a = __half22float2(p.h2[q]);
            acc += a.x * wrow[k0 + 2 * q] + a.y * wrow[k0 + 2 * q + 1];
        }
    }
    hs[gid] = acc;
}

// ====== fp32 gather for the last (F=16) layer ======
__global__ __launch_bounds__(256) void k_gather4(const unsigned* __restrict__ packed,
                                                 const unsigned short* __restrict__ eidx,
                                                 const float* __restrict__ hs,
                                                 const float* __restrict__ dinv,
                                                 const float* __restrict__ bias,
                                                 float* __restrict__ out) {
    int tid = blockIdx.x * 256 + threadIdx.x;
    int r = tid >> 2;
    if (r >= N_NODES) return;
    int l = tid & 3;
    int f = l * 4;
    const float dv = dinv[r];
    const float4 bi = *(const float4*)&bias[f];
    float4 h = *(const float4*)&hs[(size_t)r * 16 + f];
    float ax = 2.f * h.x, ay = 2.f * h.y, az = 2.f * h.z, aw = 2.f * h.w;
    unsigned pk = packed[r];
    int i = (int)(pk >> 11);
    int end = i + (int)(pk & 2047u);
    for (; i + 4 <= end; i += 4) {
        int my = (int)eidx[i + l];
#pragma unroll
        for (int j = 0; j < 4; ++j) {
            int s = __shfl(my, j, 4);
            float4 v = *(const float4*)&hs[(size_t)s * 16 + f];
            ax += v.x; ay += v.y; az += v.z; aw += v.w;
        }
    }
    if (i < end) {
        int n = end - i;
        int my = (l < n) ? (int)eidx[i + l] : 0;
        for (int j = 0; j < n; ++j) {
            int s = __shfl(my, j, 4);
            float4 v = *(const float4*)&hs[(size_t)s * 16 + f];
            ax += v.x; ay += v.y; az += v.z; aw += v.w;
        }
    }
    float v0 = tanhf(dv * ax + bi.x);
    float v1 = tanhf(dv * ay + bi.y);
    float v2 = tanhf(dv * az + bi.z);
    float v3 = tanhf(dv * aw + bi.w);
    floatx4 o = {v0, v1, v2, v3};
    __builtin_nontemporal_store(o, (floatx4*)&out[(size_t)r * 16 + f]);
}

extern "C" void kernel_launch(void* const* d_in, const int* in_sizes, int n_in,
                              void* d_out, int out_size, void* d_ws, size_t ws_size,
                              hipStream_t stream) {
    const float* x  = (const float*)d_in[0];
    const int* ei   = (const int*)d_in[1];
    const float* W0 = (const float*)d_in[2];
    const float* b0 = (const float*)d_in[3];
    const float* W1 = (const float*)d_in[4];
    const float* b1 = (const float*)d_in[5];
    const float* W2 = (const float*)d_in[6];
    const float* b2 = (const float*)d_in[7];
    const float* W3 = (const float*)d_in[8];
    const float* b3 = (const float*)d_in[9];
    const int* src = ei;
    const int* dst = ei + N_EDGES;

    // ws layout (16B-aligned):
    __half* A      = (__half*)d_ws;                        // 50000*128 f16 (ping)
    __half* P      = A + (size_t)N_NODES * 128;            // 50000*128 f16 (pong)
    __half* WT     = P + (size_t)N_NODES * 128;            // 3*128*128 f16
    float*  H16    = (float*)(WT + 3 * 128 * 128);         // 50000*16 f32
    float*  dinv   = H16 + (size_t)N_NODES * 16;           // 50000
    unsigned* packed = (unsigned*)(dinv + N_NODES);        // 50000
    int*    gcur   = (int*)(packed + N_NODES);             // 1024 (NB padded)
    unsigned short* eidx = (unsigned short*)(gcur + 1024); // NB*CAP u16
    unsigned* arena = (unsigned*)(eidx + NB * CAP);        // NB*CAP

    // ---- CSR build + prep (every call; ws is re-poisoned) ----
    (void)hipMemsetAsync(gcur, 0, 1024 * sizeof(int), stream);
    k_bucket<<<BUCKET_BLOCKS, 256, 0, stream>>>(src, dst, gcur, arena);
    k_fill3prep<<<FILL_GRID, 256, 0, stream>>>(arena, gcur, packed, dinv,
                                               eidx, x, A, W0, W1, W2, WT);

    // ---- fused layers: gather(p) -> MFMA -> p_next, ping-pong A/P ----
    k_fused<true><<<FB, 256, 0, stream>>>(A, WT, dinv, packed, eidx, b0, P);
    k_fused<false><<<FB, 256, 0, stream>>>(P, WT + 128 * 128, dinv, packed,
                                           eidx, b1, A);
    k_fused<false><<<FB, 256, 0, stream>>>(A, WT + 2 * 128 * 128, dinv, packed,
                                           eidx, b2, P);
    // ---- layer 3 (128 -> 16, tanh): gemm-first, 16-wide gather ----
    k_gemm16<<<N_NODES * 16 / 256, 256, 0, stream>>>(P, W3, H16);
    k_gather4<<<(N_NODES * 4 + 255) / 256, 256, 0, stream>>>(
        packed, eidx, H16, dinv, b3, (float*)d_out);
}

// Round 6
// 254.957 us; speedup vs baseline: 1.3176x; 1.3176x over previous
//
#include <hip/hip_runtime.h>
#include <hip/hip_fp16.h>
#include <math.h>

#define N_NODES 50000
#define N_EDGES 800000
#define NB 782            // ceil(50000/64) buckets of 64 dst nodes
#define CH 4096           // edges per k_bucket block
#define CAP 2048          // arena slots per bucket (Poisson(1024) -> 2x slack)
#define BUCKET_BLOCKS 196 // ceil(800000/4096)
#define CAST_BLOCKS 6250  // N_NODES*128/4/256
#define PREPW_BLOCKS 192  // 3 * 16384/256
#define W3_BLOCKS 8       // 2048/256 (W3 -> fp16 transpose)
#define BPREP_GRID (BUCKET_BLOCKS + CAST_BLOCKS + PREPW_BLOCKS + W3_BLOCKS)
#define FB 1563           // ceil(50000/32) fused-layer blocks (32 nodes each)

typedef _Float16 half8 __attribute__((ext_vector_type(8)));
typedef float floatx4 __attribute__((ext_vector_type(4)));
typedef unsigned uintx4 __attribute__((ext_vector_type(4)));

// ---- pass 1 (merged): bucket scatter | x->fp16 cast | W->fp16 W^T | WT3 ---
// cast/W-prep have no dependency on the bucket phase: putting them in the
// same grid overlaps their streaming traffic with the bucket blocks'
// latency-heavy LDS/atomic work, and shrinks pass 2 to finalize-only.
__global__ __launch_bounds__(256) void k_bucket_prep(
    const int* __restrict__ src, const int* __restrict__ dst,
    int* __restrict__ gcur, unsigned* __restrict__ arena,
    const float* __restrict__ x, __half* __restrict__ xh,
    const float* __restrict__ W0, const float* __restrict__ W1,
    const float* __restrict__ W2, const float* __restrict__ W3,
    __half* __restrict__ WT, __half* __restrict__ WT3) {
    const int t = threadIdx.x;
    if (blockIdx.x >= BUCKET_BLOCKS) {
        int xb = blockIdx.x - BUCKET_BLOCKS;
        if (xb < CAST_BLOCKS) {
            int i = xb * 256 + t;  // float4-granular, exact
            float4 v = *(const float4*)&x[(size_t)i * 4];
            union { ushort4 u; __half h[4]; } p;
            p.h[0] = __float2half(v.x); p.h[1] = __float2half(v.y);
            p.h[2] = __float2half(v.z); p.h[3] = __float2half(v.w);
            *(ushort4*)&xh[(size_t)i * 4] = p.u;
        } else {
            int idx = xb - CAST_BLOCKS;  // 0..199
            if (idx < PREPW_BLOCKS) {
                int which = idx >> 6;
                const float* W = (which == 0) ? W0 : (which == 1) ? W1 : W2;
                int i = (idx & 63) * 256 + t;  // i = k*128 + n
                int k = i >> 7, n = i & 127;
                int np = ((n & 7) << 4) + (n >> 3);  // perm^-1
                WT[which * 128 * 128 + np * 128 + k] = __float2half(W[i]);
            } else {
                int i = (idx - PREPW_BLOCKS) * 256 + t;  // 0..2047
                int n = i >> 7, k = i & 127;             // W3: [128][16]
                WT3[n * 128 + k] = __float2half(W3[k * 16 + n]);
            }
        }
        return;
    }
    __shared__ int cntA[NB];
    __shared__ int lofs[NB];
    __shared__ int gbase[NB];
    __shared__ int part[256];
    __shared__ unsigned buf[CH];
    const int ebase = blockIdx.x * CH;
    const int chunkN = min(CH, N_EDGES - ebase);

    for (int i = t; i < NB; i += 256) cntA[i] = 0;
    __syncthreads();
    for (int i = t; i < chunkN; i += 256)
        atomicAdd(&cntA[dst[ebase + i] >> 6], 1);
    __syncthreads();
    int c[4];
    int s = 0;
#pragma unroll
    for (int q = 0; q < 4; ++q) {
        int idx = t * 4 + q;
        c[q] = (idx < NB) ? cntA[idx] : 0;
        s += c[q];
    }
    part[t] = s;
    __syncthreads();
    for (int d = 1; d < 256; d <<= 1) {
        int u = (t >= d) ? part[t - d] : 0;
        __syncthreads();
        part[t] += u;
        __syncthreads();
    }
    int run = (t > 0) ? part[t - 1] : 0;
#pragma unroll
    for (int q = 0; q < 4; ++q) {
        int idx = t * 4 + q;
        if (idx < NB) {
            lofs[idx] = run;
            run += c[q];
            gbase[idx] = (c[q] > 0) ? atomicAdd(&gcur[idx], c[q]) : 0;
            cntA[idx] = 0;  // reuse as placement cursor
        }
    }
    __syncthreads();
    for (int i = t; i < chunkN; i += 256) {
        int d = dst[ebase + i];
        int sv = src[ebase + i];
        int b = d >> 6;
        int pos = atomicAdd(&cntA[b], 1);
        buf[lofs[b] + pos] = ((unsigned)d << 16) | (unsigned)sv;
    }
    __syncthreads();
    for (int i = t; i < chunkN; i += 256) {
        unsigned v = buf[i];
        int b = (int)(v >> 16) >> 6;
        int q = i - lofs[b];
        int p = gbase[b] + q;
        if (p < CAP) arena[((size_t)b << 11) + p] = v;
    }
}

// ---- pass 2: bucket finalize only (dinv, packed, eidx) --------------------
__global__ __launch_bounds__(256) void k_fill(
    const unsigned* __restrict__ arena, const int* __restrict__ gcur,
    unsigned* __restrict__ packed, float* __restrict__ dinv,
    unsigned short* __restrict__ eidx) {
    const int t = threadIdx.x;
    const int b = blockIdx.x;
    __shared__ int cnt64[64];
    __shared__ int cur64[64];
    if (t < 64) cnt64[t] = 0;
    __syncthreads();
    const int seglen = min(gcur[b], CAP);
    const unsigned* seg = arena + ((size_t)b << 11);
    for (int i = t; i < seglen; i += 256)
        atomicAdd(&cnt64[(seg[i] >> 16) & 63], 1);
    __syncthreads();
    if (t < 64) {  // one wave: prefix scan of 64 counts
        int v = cnt64[t];
        int p = v;
#pragma unroll
        for (int d = 1; d < 64; d <<= 1) {
            int u = __shfl_up(p, d, 64);
            if (t >= d) p += u;
        }
        int excl = p - v;
        int node = b * 64 + t;
        if (node < N_NODES) {
            packed[node] = ((unsigned)((b << 11) + excl) << 11) | (unsigned)v;
            dinv[node] = rsqrtf((float)v + 2.0f);  // improved: +2
        }
        cur64[t] = excl;
    }
    __syncthreads();
    const int base = b << 11;
    for (int i = t; i < seglen; i += 256) {
        unsigned v = seg[i];
        int d = (int)(v >> 16) & 63;
        int pos = atomicAdd(&cur64[d], 1);
        eidx[base + pos] = (unsigned short)(v & 0xFFFFu);
    }
}

// ---- scaled 256B-row accumulate: acc[0..15] += s * row -------------------
__device__ __forceinline__ void accs(uint4 ua, uint4 ub, float s, float* acc) {
    union { uint4 u; __half2 h2[4]; } va, vb;
    va.u = ua; vb.u = ub;
#pragma unroll
    for (int q = 0; q < 4; ++q) {
        float2 wa = __half22float2(va.h2[q]);
        float2 wb = __half22float2(vb.h2[q]);
        acc[2 * q]     += s * wa.x;
        acc[2 * q + 1] += s * wa.y;
        acc[8 + 2 * q]     += s * wb.x;
        acc[8 + 2 * q + 1] += s * wb.y;
    }
}

// ---- shared gather stage: acc = 2*p_r (+dinv scaling) + sum p_src ---------
// Round-4 geometry (best measured): 32 nodes/block, 8 lanes/node, 16-edge
// batches = 16 outstanding uint4/lane. launch_bounds(256,2): let the
// allocator keep the staging in flight (VGPR ~76 -> 4 waves/SIMD); the
// forced (256,8) variant collapsed to VGPR 32 and serialized (round 5).
template <bool SC>
__device__ __forceinline__ void gather_stage(
    int r, bool valid, int l8, const __half* __restrict__ pin,
    const float* __restrict__ dinv, const unsigned* __restrict__ packed,
    const unsigned short* __restrict__ eidx, float* acc) {
#pragma unroll
    for (int j = 0; j < 16; ++j) acc[j] = 0.f;
    int i = 0, end = 0;
    if (valid) {
        const uint4* rp = (const uint4*)&pin[(size_t)r * 128];
        uint4 sa = rp[l8], sb = rp[8 + l8];
        float s2 = SC ? 2.f * dinv[r] : 2.f;
        accs(sa, sb, s2, acc);
        unsigned pk = packed[r];
        i = (int)(pk >> 11);
        end = i + (int)(pk & 2047u);
    }
    for (; i + 8 <= end; i += 8) {
        int my = (int)eidx[i + l8];
        uint4 va[8], vb[8];
        float ds8[8];
#pragma unroll
        for (int j = 0; j < 8; ++j) {
            int s0 = __shfl(my, j, 8);
            const uint4* q = (const uint4*)&pin[(size_t)s0 * 128];
            va[j] = q[l8];
            vb[j] = q[8 + l8];
            if (SC) ds8[j] = dinv[s0];
        }
#pragma unroll
        for (int j = 0; j < 8; ++j)
            accs(va[j], vb[j], SC ? ds8[j] : 1.f, acc);
    }
    if (i < end) {
        int n = end - i;
        int my = (l8 < n) ? (int)eidx[i + l8] : 0;
        for (int j = 0; j < n; ++j) {
            int s0 = __shfl(my, j, 8);
            const uint4* q = (const uint4*)&pin[(size_t)s0 * 128];
            accs(q[l8], q[8 + l8], SC ? dinv[s0] : 1.f, acc);
        }
    }
}

// ====== fused layer: t = 2*p_r + sum p_src  ->  p_next = relu(dv*(dv*tW+b))
template <bool SC>
__global__ __launch_bounds__(256, 2) void k_fused(
    const __half* __restrict__ pin, const __half* __restrict__ WTl,
    const float* __restrict__ dinv, const unsigned* __restrict__ packed,
    const unsigned short* __restrict__ eidx, const float* __restrict__ bias,
    __half* __restrict__ pout) {
    __shared__ __half tl[32 * 136];  // +8 pad: conflict-free b128 r/w
    const int t = threadIdx.x;
    const int node8 = t >> 3;
    const int l8 = t & 7;
    const int r = blockIdx.x * 32 + node8;

    float acc[16];
    gather_stage<SC>(r, r < N_NODES, l8, pin, dinv, packed, eidx, acc);

    {
        union { uintx4 u; __half h[8]; } pa, pb;
#pragma unroll
        for (int j = 0; j < 8; ++j) {
            pa.h[j] = __float2half(acc[j]);
            pb.h[j] = __float2half(acc[8 + j]);
        }
        *(uintx4*)&tl[node8 * 136 + 8 * l8] = pa.u;
        *(uintx4*)&tl[node8 * 136 + 64 + 8 * l8] = pb.u;
    }
    __syncthreads();

    // MFMA: 4 waves = 2 row-tiles x 2 col-tiles; 16 mfma each
    const int wave = t >> 6;
    const int lane = t & 63;
    const int m = lane & 15;
    const int quad = lane >> 4;
    const int rtile = wave >> 1;
    const int ctile = wave & 1;
    floatx4 a4[4] = {};
#pragma unroll
    for (int kb = 0; kb < 4; ++kb) {
        half8 af = *(const half8*)&tl[(rtile * 16 + m) * 136 + quad * 8 + kb * 32];
#pragma unroll
        for (int j = 0; j < 4; ++j) {
            half8 bf = *(const half8*)&WTl[(size_t)(((ctile * 4 + j) * 16 + m)) * 128 +
                                           kb * 32 + quad * 8];
            a4[j] = __builtin_amdgcn_mfma_f32_16x16x32_f16(af, bf, a4[j], 0, 0, 0);
        }
    }
    // feature f = 8m + ctile*4 + j ; node = base + rtile*16 + quad*4 + rr
    const int f0 = 8 * m + ctile * 4;
    const float4 bi = *(const float4*)&bias[f0];
    const int nb0 = blockIdx.x * 32 + rtile * 16 + quad * 4;
#pragma unroll
    for (int rr = 0; rr < 4; ++rr) {
        int node = nb0 + rr;
        if (node < N_NODES) {
            float dv = dinv[node];
            union { ushort4 u; __half h[4]; } pk4;
            pk4.h[0] = __float2half(fmaxf(dv * (dv * a4[0][rr] + bi.x), 0.f));
            pk4.h[1] = __float2half(fmaxf(dv * (dv * a4[1][rr] + bi.y), 0.f));
            pk4.h[2] = __float2half(fmaxf(dv * (dv * a4[2][rr] + bi.z), 0.f));
            pk4.h[3] = __float2half(fmaxf(dv * (dv * a4[3][rr] + bi.w), 0.f));
            *(ushort4*)&pout[(size_t)node * 128 + f0] = pk4.u;
        }
    }
}

// ====== last fused layer: gather + GEMM(W2) + relu + GEMM(W3) -> H16 =======
// The block holds the whole 32x128 p3 tile; fusing the 128->16 transform
// here kills the gemm16 dispatch and the 25.6 MB p3 round-trip.
__global__ __launch_bounds__(256, 2) void k_fused_last(
    const __half* __restrict__ pin, const __half* __restrict__ WTl,
    const __half* __restrict__ WT3, const float* __restrict__ dinv,
    const unsigned* __restrict__ packed, const unsigned short* __restrict__ eidx,
    const float* __restrict__ bias, float* __restrict__ H16) {
    __shared__ __half tl[32 * 136];
    const int t = threadIdx.x;
    const int node8 = t >> 3;
    const int l8 = t & 7;
    const int r = blockIdx.x * 32 + node8;

    float acc[16];
    gather_stage<false>(r, r < N_NODES, l8, pin, dinv, packed, eidx, acc);

    {
        union { uintx4 u; __half h[8]; } pa, pb;
#pragma unroll
        for (int j = 0; j < 8; ++j) {
            pa.h[j] = __float2half(acc[j]);
            pb.h[j] = __float2half(acc[8 + j]);
        }
        *(uintx4*)&tl[node8 * 136 + 8 * l8] = pa.u;
        *(uintx4*)&tl[node8 * 136 + 64 + 8 * l8] = pb.u;
    }
    __syncthreads();

    const int wave = t >> 6;
    const int lane = t & 63;
    const int m = lane & 15;
    const int quad = lane >> 4;
    const int rtile = wave >> 1;
    const int ctile = wave & 1;
    floatx4 a4[4] = {};
#pragma unroll
    for (int kb = 0; kb < 4; ++kb) {
        half8 af = *(const half8*)&tl[(rtile * 16 + m) * 136 + quad * 8 + kb * 32];
#pragma unroll
        for (int j = 0; j < 4; ++j) {
            half8 bf = *(const half8*)&WTl[(size_t)(((ctile * 4 + j) * 16 + m)) * 128 +
                                           kb * 32 + quad * 8];
            a4[j] = __builtin_amdgcn_mfma_f32_16x16x32_f16(af, bf, a4[j], 0, 0, 0);
        }
    }
    __syncthreads();  // everyone done reading tl; reuse it for the p3 tile

    // p3 = relu(dv*(dv*a4+b2)) -> LDS (fp16, same rounding as before)
    const int f0 = 8 * m + ctile * 4;
    const float4 bi = *(const float4*)&bias[f0];
    const int rowb = rtile * 16 + quad * 4;
#pragma unroll
    for (int rr = 0; rr < 4; ++rr) {
        int node = blockIdx.x * 32 + rowb + rr;
        float dv = (node < N_NODES) ? dinv[node] : 0.f;
        union { ushort4 u; __half h[4]; } pk4;
        pk4.h[0] = __float2half(fmaxf(dv * (dv * a4[0][rr] + bi.x), 0.f));
        pk4.h[1] = __float2half(fmaxf(dv * (dv * a4[1][rr] + bi.y), 0.f));
        pk4.h[2] = __float2half(fmaxf(dv * (dv * a4[2][rr] + bi.z), 0.f));
        pk4.h[3] = __float2half(fmaxf(dv * (dv * a4[3][rr] + bi.w), 0.f));
        *(ushort4*)&tl[(rowb + rr) * 136 + f0] = pk4.u;
    }
    __syncthreads();

    // second MFMA: M=32 x N=16 x K=128 on waves 0-1 (wave = row-tile)
    if (wave < 2) {
        floatx4 c2 = {};
#pragma unroll
        for (int kb = 0; kb < 4; ++kb) {
            half8 af2 = *(const half8*)&tl[(wave * 16 + m) * 136 + quad * 8 + kb * 32];
            half8 bf2 = *(const half8*)&WT3[(size_t)m * 128 + kb * 32 + quad * 8];
            c2 = __builtin_amdgcn_mfma_f32_16x16x32_f16(af2, bf2, c2, 0, 0, 0);
        }
        // C layout: col = m (output class), row = quad*4 + rr
#pragma unroll
        for (int rr = 0; rr < 4; ++rr) {
            int node = blockIdx.x * 32 + wave * 16 + quad * 4 + rr;
            if (node < N_NODES) H16[(size_t)node * 16 + m] = c2[rr];
        }
    }
}

// ====== fp32 gather for the last (F=16) layer ======
__global__ __launch_bounds__(256) void k_gather4(const unsigned* __restrict__ packed,
                                                 const unsigned short* __restrict__ eidx,
                                                 const float* __restrict__ hs,
                                                 const float* __restrict__ dinv,
                                                 const float* __restrict__ bias,
                                                 float* __restrict__ out) {
    int tid = blockIdx.x * 256 + threadIdx.x;
    int r = tid >> 2;
    if (r >= N_NODES) return;
    int l = tid & 3;
    int f = l * 4;
    const float dv = dinv[r];
    const float4 bi = *(const float4*)&bias[f];
    float4 h = *(const float4*)&hs[(size_t)r * 16 + f];
    float ax = 2.f * h.x, ay = 2.f * h.y, az = 2.f * h.z, aw = 2.f * h.w;
    unsigned pk = packed[r];
    int i = (int)(pk >> 11);
    int end = i + (int)(pk & 2047u);
    for (; i + 4 <= end; i += 4) {
        int my = (int)eidx[i + l];
#pragma unroll
        for (int j = 0; j < 4; ++j) {
            int s = __shfl(my, j, 4);
            float4 v = *(const float4*)&hs[(size_t)s * 16 + f];
            ax += v.x; ay += v.y; az += v.z; aw += v.w;
        }
    }
    if (i < end) {
        int n = end - i;
        int my = (l < n) ? (int)eidx[i + l] : 0;
        for (int j = 0; j < n; ++j) {
            int s = __shfl(my, j, 4);
            float4 v = *(const float4*)&hs[(size_t)s * 16 + f];
            ax += v.x; ay += v.y; az += v.z; aw += v.w;
        }
    }
    float v0 = tanhf(dv * ax + bi.x);
    float v1 = tanhf(dv * ay + bi.y);
    float v2 = tanhf(dv * az + bi.z);
    float v3 = tanhf(dv * aw + bi.w);
    floatx4 o = {v0, v1, v2, v3};
    __builtin_nontemporal_store(o, (floatx4*)&out[(size_t)r * 16 + f]);
}

extern "C" void kernel_launch(void* const* d_in, const int* in_sizes, int n_in,
                              void* d_out, int out_size, void* d_ws, size_t ws_size,
                              hipStream_t stream) {
    const float* x  = (const float*)d_in[0];
    const int* ei   = (const int*)d_in[1];
    const float* W0 = (const float*)d_in[2];
    const float* b0 = (const float*)d_in[3];
    const float* W1 = (const float*)d_in[4];
    const float* b1 = (const float*)d_in[5];
    const float* W2 = (const float*)d_in[6];
    const float* b2 = (const float*)d_in[7];
    const float* W3 = (const float*)d_in[8];
    const float* b3 = (const float*)d_in[9];
    const int* src = ei;
    const int* dst = ei + N_EDGES;

    // ws layout (16B-aligned):
    __half* A      = (__half*)d_ws;                        // 50000*128 f16 (ping)
    __half* P      = A + (size_t)N_NODES * 128;            // 50000*128 f16 (pong)
    __half* WT     = P + (size_t)N_NODES * 128;            // 3*128*128 f16
    __half* WT3    = WT + 3 * 128 * 128;                   // 16*128 f16
    float*  H16    = (float*)(WT3 + 16 * 128);             // 50000*16 f32
    float*  dinv   = H16 + (size_t)N_NODES * 16;           // 50000
    unsigned* packed = (unsigned*)(dinv + N_NODES);        // 50000
    int*    gcur   = (int*)(packed + N_NODES);             // 1024 (NB padded)
    unsigned short* eidx = (unsigned short*)(gcur + 1024); // NB*CAP u16
    unsigned* arena = (unsigned*)(eidx + NB * CAP);        // NB*CAP

    // ---- CSR build + prep (every call; ws is re-poisoned) ----
    (void)hipMemsetAsync(gcur, 0, 1024 * sizeof(int), stream);
    k_bucket_prep<<<BPREP_GRID, 256, 0, stream>>>(src, dst, gcur, arena, x, A,
                                                  W0, W1, W2, W3, WT, WT3);
    k_fill<<<NB, 256, 0, stream>>>(arena, gcur, packed, dinv, eidx);

    // ---- fused layers: gather(p) -> MFMA -> p_next ----
    k_fused<true><<<FB, 256, 0, stream>>>(A, WT, dinv, packed, eidx, b0, P);
    k_fused<false><<<FB, 256, 0, stream>>>(P, WT + 128 * 128, dinv, packed,
                                           eidx, b1, A);
    // ---- layer 2 + layer-3 dense transform fused ----
    k_fused_last<<<FB, 256, 0, stream>>>(A, WT + 2 * 128 * 128, WT3, dinv,
                                         packed, eidx, b2, H16);
    // ---- layer 3 aggregate (F=16, tanh) ----
    k_gather4<<<(N_NODES * 4 + 255) / 256, 256, 0, stream>>>(
        packed, eidx, H16, dinv, b3, (float*)d_out);
}